// Round 8
// baseline (1407.426 us; speedup 1.0000x reference)
//
#include <hip/hip_runtime.h>

// Autoregressive FFNN. out[b,0]=0; t=1..511: mi=[x[b,t,:],pred]; h=relu(mi@W1+b1); pred=h@W2+b2.
// B=4096,T=512,F=63. R7: 512 WGs x 512 thr (8 waves), 8 batch rows/WG -> TWO independent
// WGs per CU (independent serial chains interleave; R6 showed intra-WG waves can't hide
// each other's latency). MFMA upper 8 rows are zero/wasted; net VALU issue/CU ~2x R5 but
// fills the ~55% stall fraction. Kept from R5: raw s_barrier + lgkmcnt-only drain,
// LDS bf16 x-staging, b1 folded into MFMA k=63 slot, VALU pred feedback, shfl_xor reduces.

#define TT 512
#define FF 63
#define HID 1024
#define ROWS 8

typedef __attribute__((ext_vector_type(8))) short short8;
typedef __attribute__((ext_vector_type(4))) float f32x4;

__device__ __forceinline__ unsigned short f2bf(float f) {
  union { float f; unsigned u; } v; v.f = f;
  unsigned r = v.u + 0x7FFFu + ((v.u >> 16) & 1u);  // RNE
  return (unsigned short)(r >> 16);
}

// LDS-visibility barrier WITHOUT the vmcnt(0) drain of __syncthreads.
__device__ __forceinline__ void lds_barrier() {
  asm volatile("s_waitcnt lgkmcnt(0)" ::: "memory");
  __builtin_amdgcn_s_barrier();
  asm volatile("" ::: "memory");
}

// butterfly stage: v[q] += shfl_xor(v[q], M) (proven R1/R4/R5)
template<int M>
__device__ __forceinline__ f32x4 sflxadd4(f32x4 v) {
  f32x4 r;
#pragma unroll
  for (int q = 0; q < 4; ++q) r[q] = v[q] + __shfl_xor(v[q], M, 64);
  return r;
}

__global__ __launch_bounds__(512, 4)
void ffnn_ar_kernel(const float* __restrict__ x,
                    const float* __restrict__ W1,
                    const float* __restrict__ b1,
                    const float* __restrict__ W2,
                    const float* __restrict__ b2p,
                    float* __restrict__ out) {
  __shared__ __align__(16) unsigned short lds_A[2][16][72];  // bf16 x-tiles; rows 8..15 zero
  __shared__ __align__(16) float lds_part[2][8][20];         // [buf][wave][16 rows + pad]

  const int tid  = threadIdx.x;
  const int lane = tid & 63;
  const int w    = tid >> 6;    // wave 0..7: owns hidden cols [128w, 128w+128)
  const int c    = lane & 15;   // A row (batch row) / hidden sub-col
  const int g    = lane >> 4;   // k-group / acc row-block
  const int br   = blockIdx.x * ROWS;

  // ---- weights (one-time): 8 N-tiles per wave; b1 in k=63 slot ----
  short8 bfr[8][2];
  float  w63f[8], w2f[8];
#pragma unroll
  for (int i = 0; i < 8; ++i) {
    const int n = (w * 8 + i) * 16 + c;
#pragma unroll
    for (int ks = 0; ks < 2; ++ks) {
      short8 f;
#pragma unroll
      for (int j = 0; j < 8; ++j) {
        const int k = ks * 32 + g * 8 + j;
        const float val = (k == 63) ? b1[n] : W1[k * HID + n];
        f[j] = (short)f2bf(val);
      }
      bfr[i][ks] = f;
    }
    w63f[i] = W1[63 * HID + n];
    w2f[i]  = W2[n];
  }
  const float b2 = b2p[0];

  // ---- x staging: wave w stages batch row w (8 rows); elem = lane (0..62) ----
  const long rowbase = (long)(br + w) * (TT * FF);
  const bool st = (lane < 63);

  // prologue: zero rows 8..15 (both buffers, all 72 cols) so MFMA upper half is clean
  if (tid < 288) {
    const int r  = 8 + tid / 36;
    const int cc = (tid % 36) * 2;
    *reinterpret_cast<unsigned*>(&lds_A[0][r][cc]) = 0u;
    *reinterpret_cast<unsigned*>(&lds_A[1][r][cc]) = 0u;
  }
  // stage x_1 -> buf1; col63 = 1.0 for valid rows; part buf0 = 0 with chunk0 = -b2
  if (st) lds_A[1][w][lane] = f2bf(x[rowbase + FF + lane]);
  if (tid < 8) { lds_A[0][tid][63] = 0x3F80; lds_A[1][tid][63] = 0x3F80; }
  if (tid < 320) reinterpret_cast<float*>(lds_part)[tid] = 0.f;
  if (tid < 16) lds_part[0][0][tid] = -b2;  // sum over waves + b2 = 0 => pred_0 = 0

  // 2 prefetch sets: S0 = x_2, S1 = x_3
  float s0 = st ? x[rowbase + 2 * FF + lane] : 0.f;
  float s1 = st ? x[rowbase + 3 * FF + lane] : 0.f;

  lds_barrier();

#define STEP(T, CUR, S)                                                            \
  {                                                                                \
    /* A-frags for x_T */                                                          \
    const short8 a0 = *reinterpret_cast<const short8*>(&lds_A[CUR][c][g * 8]);     \
    const short8 a1 = *reinterpret_cast<const short8*>(&lds_A[CUR][c][32 + g * 8]);\
    /* pred_{T-1}: 8 independent b128 reads + tree; lane gets rows g*4..g*4+3 */   \
    f32x4 q0 = *reinterpret_cast<const f32x4*>(&lds_part[(CUR) ^ 1][0][g * 4]);    \
    f32x4 q1 = *reinterpret_cast<const f32x4*>(&lds_part[(CUR) ^ 1][1][g * 4]);    \
    f32x4 q2 = *reinterpret_cast<const f32x4*>(&lds_part[(CUR) ^ 1][2][g * 4]);    \
    f32x4 q3 = *reinterpret_cast<const f32x4*>(&lds_part[(CUR) ^ 1][3][g * 4]);    \
    f32x4 q4 = *reinterpret_cast<const f32x4*>(&lds_part[(CUR) ^ 1][4][g * 4]);    \
    f32x4 q5 = *reinterpret_cast<const f32x4*>(&lds_part[(CUR) ^ 1][5][g * 4]);    \
    f32x4 q6 = *reinterpret_cast<const f32x4*>(&lds_part[(CUR) ^ 1][6][g * 4]);    \
    f32x4 q7 = *reinterpret_cast<const f32x4*>(&lds_part[(CUR) ^ 1][7][g * 4]);    \
    f32x4 pr = ((q0 + q1) + (q2 + q3)) + ((q4 + q5) + (q6 + q7));                  \
    const float p0 = pr[0] + b2, p1 = pr[1] + b2;                                  \
    const float p2 = pr[2] + b2, p3 = pr[3] + b2;                                  \
    f32x4 acc[8];                                                                  \
    _Pragma("unroll") for (int i = 0; i < 8; ++i) {                                \
      f32x4 z4 = {0.f, 0.f, 0.f, 0.f};                                             \
      z4 = __builtin_amdgcn_mfma_f32_16x16x32_bf16(a0, bfr[i][0], z4, 0, 0, 0);    \
      z4 = __builtin_amdgcn_mfma_f32_16x16x32_bf16(a1, bfr[i][1], z4, 0, 0, 0);    \
      acc[i] = z4;                                                                 \
    }                                                                              \
    /* store pred_{T-1}: wave0, c==0, valid rows g*4+q < 8 (g<2) */                \
    if (w == 0 && c == 0 && g < 2) {                                               \
      out[(long)(br + g * 4 + 0) * TT + ((T) - 1)] = p0;                           \
      out[(long)(br + g * 4 + 1) * TT + ((T) - 1)] = p1;                           \
      out[(long)(br + g * 4 + 2) * TT + ((T) - 1)] = p2;                           \
      out[(long)(br + g * 4 + 3) * TT + ((T) - 1)] = p3;                           \
    }                                                                              \
    /* stage x_{T+1} from prefetch reg (loaded 2 steps ago) */                     \
    if (st) lds_A[(CUR) ^ 1][w][lane] = f2bf(S);                                   \
    /* reload reg <- x_{T+3} (stays in flight across raw barriers) */              \
    {                                                                              \
      const int tp = ((T) + 3 < TT) ? (T) + 3 : TT - 1;                            \
      if (st) S = x[rowbase + (long)tp * FF + lane];                               \
    }                                                                              \
    /* layer2: z = acc(+b1 in MFMA) + pred*w63 ; h=relu ; part += h*w2 */          \
    f32x4 part = {0.f, 0.f, 0.f, 0.f};                                             \
    _Pragma("unroll") for (int i = 0; i < 8; ++i) {                                \
      part[0] = fmaf(fmaxf(fmaf(p0, w63f[i], acc[i][0]), 0.f), w2f[i], part[0]);   \
      part[1] = fmaf(fmaxf(fmaf(p1, w63f[i], acc[i][1]), 0.f), w2f[i], part[1]);   \
      part[2] = fmaf(fmaxf(fmaf(p2, w63f[i], acc[i][2]), 0.f), w2f[i], part[2]);   \
      part[3] = fmaf(fmaxf(fmaf(p3, w63f[i], acc[i][3]), 0.f), w2f[i], part[3]);   \
    }                                                                              \
    part = sflxadd4<1>(part); part = sflxadd4<2>(part);                            \
    part = sflxadd4<4>(part); part = sflxadd4<8>(part);                            \
    if (c == 0) *reinterpret_cast<f32x4*>(&lds_part[CUR][w][g * 4]) = part;        \
    lds_barrier();                                                                 \
  }

#pragma unroll 1
  for (int t = 1; t + 1 < TT; t += 2) {
    STEP(t, 1, s0)
    STEP(t + 1, 0, s1)
  }
  STEP(TT - 1, 1, s0)  // t = 511 (odd, CUR=1, writes part[1])

  // final: gather pred_511 from part[1] and store out[., 511]
  {
    f32x4 q0 = *reinterpret_cast<const f32x4*>(&lds_part[1][0][g * 4]);
    f32x4 q1 = *reinterpret_cast<const f32x4*>(&lds_part[1][1][g * 4]);
    f32x4 q2 = *reinterpret_cast<const f32x4*>(&lds_part[1][2][g * 4]);
    f32x4 q3 = *reinterpret_cast<const f32x4*>(&lds_part[1][3][g * 4]);
    f32x4 q4 = *reinterpret_cast<const f32x4*>(&lds_part[1][4][g * 4]);
    f32x4 q5 = *reinterpret_cast<const f32x4*>(&lds_part[1][5][g * 4]);
    f32x4 q6 = *reinterpret_cast<const f32x4*>(&lds_part[1][6][g * 4]);
    f32x4 q7 = *reinterpret_cast<const f32x4*>(&lds_part[1][7][g * 4]);
    f32x4 pr = ((q0 + q1) + (q2 + q3)) + ((q4 + q5) + (q6 + q7));
    if (w == 0 && c == 0 && g < 2) {
#pragma unroll
      for (int q = 0; q < 4; ++q)
        out[(long)(br + g * 4 + q) * TT + (TT - 1)] = pr[q] + b2;
    }
  }
#undef STEP
}

extern "C" void kernel_launch(void* const* d_in, const int* in_sizes, int n_in,
                              void* d_out, int out_size, void* d_ws, size_t ws_size,
                              hipStream_t stream) {
  const float* x   = (const float*)d_in[0];
  // d_in[1] = labels (unused by the reference forward pass)
  const float* W1  = (const float*)d_in[2];
  const float* b1  = (const float*)d_in[3];
  const float* W2  = (const float*)d_in[4];
  const float* b2  = (const float*)d_in[5];
  float* out = (float*)d_out;

  ffnn_ar_kernel<<<512, 512, 0, stream>>>(x, W1, b1, W2, b2, out);
}

// Round 9
// 515.305 us; speedup vs baseline: 2.7312x; 2.7312x over previous
//
#include <hip/hip_runtime.h>

// Autoregressive FFNN. out[b,0]=0; t=1..511: mi=[x[b,t,:],pred]; h=relu(mi@W1+b1); pred=h@W2+b2.
// B=4096,T=512,F=63. 256 WGs x 512 thr (8 waves), 16 rows/WG, persistent, 1 raw barrier/step.
// R8: operand-swapped MFMA. A=W1^T (bfr, same layout as before), B=x-frag -> z[hidden][batch=c].
//  - pred feedback injected into B-frag k=63 slot (bf16) -> no VALU feedback, no w63 regs.
//  - b1 enters as MFMA C-init (b1v). Layer-2 = 4 chained MFMAs with replicated-row W2 frags
//    whose k-slot permutation matches h's natural (i,g,q) layout -> butterfly deleted.
//  - cross-wave: 16 b32 writes (g==0) + 8 broadcast b32 reads + 7 adds.

#define TT 512
#define FF 63
#define HID 1024

typedef __attribute__((ext_vector_type(8))) short short8;
typedef __attribute__((ext_vector_type(4))) float f32x4;
typedef __attribute__((ext_vector_type(4))) int i32x4;

__device__ __forceinline__ unsigned short f2bf(float f) {
  union { float f; unsigned u; } v; v.f = f;
  unsigned r = v.u + 0x7FFFu + ((v.u >> 16) & 1u);  // RNE
  return (unsigned short)(r >> 16);
}
__device__ __forceinline__ unsigned pk2(float a, float b) {
  return ((unsigned)f2bf(b) << 16) | (unsigned)f2bf(a);
}

// LDS-visibility barrier WITHOUT the vmcnt(0) drain of __syncthreads.
__device__ __forceinline__ void lds_barrier() {
  asm volatile("s_waitcnt lgkmcnt(0)" ::: "memory");
  __builtin_amdgcn_s_barrier();
  asm volatile("" ::: "memory");
}

__global__ __launch_bounds__(512, 2)
void ffnn_ar_kernel(const float* __restrict__ x,
                    const float* __restrict__ W1,
                    const float* __restrict__ b1,
                    const float* __restrict__ W2,
                    const float* __restrict__ b2p,
                    float* __restrict__ out) {
  __shared__ __align__(16) unsigned short lds_A[2][16][72];  // bf16 x-tiles (col63 unused)
  __shared__ __align__(16) float lds_part[2][8][16];         // [buf][wave][batch c]

  const int tid  = threadIdx.x;
  const int lane = tid & 63;
  const int w    = tid >> 6;    // wave 0..7: hidden cols [128w, 128w+128)
  const int c    = lane & 15;   // batch column (C col) / frag row-id
  const int g    = lane >> 4;   // k-group
  const int br   = blockIdx.x * 16;

  // ---- one-time weights ----
  // bfr[i][ks]: A1-frag = W1^T: lane (c,g) slot j = W1[ks*32+g*8+j][(w*8+i)*16+c]
  short8 bfr[8][2];
#pragma unroll
  for (int i = 0; i < 8; ++i) {
    const int n = (w * 8 + i) * 16 + c;
#pragma unroll
    for (int ks = 0; ks < 2; ++ks) {
      short8 f;
#pragma unroll
      for (int j = 0; j < 8; ++j) f[j] = (short)f2bf(W1[(ks * 32 + g * 8 + j) * HID + n]);
      bfr[i][ks] = f;
    }
  }
  // b1v[i]: C-init, lane (c,g) reg q = b1[(w*8+i)*16 + g*4 + q]
  f32x4 b1v[8];
#pragma unroll
  for (int i = 0; i < 8; ++i) {
    const int nb = (w * 8 + i) * 16 + g * 4;
    b1v[i] = (f32x4){b1[nb], b1[nb + 1], b1[nb + 2], b1[nb + 3]};
  }
  // a2f[i2]: A2-frag (rows replicated): slot j = W2[(w*8+2*i2+(j>>2))*16 + g*4 + (j&3)]
  short8 a2f[4];
#pragma unroll
  for (int i2 = 0; i2 < 4; ++i2) {
    short8 f;
#pragma unroll
    for (int j = 0; j < 8; ++j)
      f[j] = (short)f2bf(W2[(w * 8 + 2 * i2 + (j >> 2)) * 16 + g * 4 + (j & 3)]);
    a2f[i2] = f;
  }
  const float b2 = b2p[0];
  const float b2w = (w == 0) ? b2 : 0.f;  // baked once via wave0's layer-2 C-init

  // ---- x staging: 16 groups of 32 threads, one row each (R5-proven) ----
  const int srow = tid >> 5;   // 0..15
  const int sl   = tid & 31;   // 0..31
  const long rowbase = (long)(br + srow) * (TT * FF);

  // prologue
  lds_A[1][srow][sl] = f2bf(x[rowbase + FF + sl]);
  if (sl < 31) lds_A[1][srow][32 + sl] = f2bf(x[rowbase + FF + 32 + sl]);
  if (tid < 128) reinterpret_cast<float*>(lds_part)[tid] = 0.f;  // buf0 = 0 -> pred_0 = 0
  if (tid < 16) out[(long)(br + tid) * TT] = 0.f;                // out[:,0] = 0

  float s0a = x[rowbase + 2 * FF + sl];
  float s0b = (sl < 31) ? x[rowbase + 2 * FF + 32 + sl] : 0.f;
  float s1a = x[rowbase + 3 * FF + sl];
  float s1b = (sl < 31) ? x[rowbase + 3 * FF + 32 + sl] : 0.f;

  lds_barrier();

#define STEP(T, CUR, SA, SB)                                                        \
  {                                                                                 \
    /* gather pred_{T-1}[batch c]: 8 broadcast b32 reads + tree (b2 already baked)*/\
    const float* pp = &lds_part[(CUR) ^ 1][0][c];                                   \
    const float pc = ((pp[0] + pp[16]) + (pp[32] + pp[48])) +                       \
                     ((pp[64] + pp[80]) + (pp[96] + pp[112]));                      \
    if (w == 0 && g == 0) out[(long)(br + c) * TT + ((T) - 1)] = pc;                \
    /* B-frags for x_T; inject pred into k=63 slot (g==3, elem 7) */                \
    const short8 xb0 = *reinterpret_cast<const short8*>(&lds_A[CUR][c][g * 8]);     \
    short8 xb1 = *reinterpret_cast<const short8*>(&lds_A[CUR][c][32 + g * 8]);      \
    if (g == 3) xb1[7] = (short)f2bf(pc);                                           \
    /* layer1: A=W1^T (bfr), B=x, C-init=b1 -> z[hidden g*4+q + 16i][batch c] */    \
    f32x4 acc[8];                                                                   \
    _Pragma("unroll") for (int i = 0; i < 8; ++i) {                                 \
      f32x4 z4 = __builtin_amdgcn_mfma_f32_16x16x32_bf16(bfr[i][0], xb0, b1v[i], 0, 0, 0); \
      acc[i] = __builtin_amdgcn_mfma_f32_16x16x32_bf16(bfr[i][1], xb1, z4, 0, 0, 0);\
    }                                                                               \
    /* stage x_{T+1}; prefetch x_{T+3} (stays in flight across raw barrier) */      \
    lds_A[(CUR) ^ 1][srow][sl] = f2bf(SA);                                          \
    if (sl < 31) lds_A[(CUR) ^ 1][srow][32 + sl] = f2bf(SB);                        \
    {                                                                               \
      const int tp = ((T) + 3 < TT) ? (T) + 3 : TT - 1;                             \
      SA = x[rowbase + (long)tp * FF + sl];                                         \
      if (sl < 31) SB = x[rowbase + (long)tp * FF + 32 + sl];                       \
    }                                                                               \
    /* h = relu(z), packed to bf16 in layer-2 B-frag slot order */                  \
    f32x4 p2 = {b2w, b2w, b2w, b2w};                                                \
    _Pragma("unroll") for (int i2 = 0; i2 < 4; ++i2) {                              \
      const f32x4 u = acc[2 * i2], v = acc[2 * i2 + 1];                             \
      const short8 hf = __builtin_bit_cast(short8, (i32x4){                         \
          (int)pk2(fmaxf(u[0], 0.f), fmaxf(u[1], 0.f)),                             \
          (int)pk2(fmaxf(u[2], 0.f), fmaxf(u[3], 0.f)),                             \
          (int)pk2(fmaxf(v[0], 0.f), fmaxf(v[1], 0.f)),                             \
          (int)pk2(fmaxf(v[2], 0.f), fmaxf(v[3], 0.f))});                           \
      p2 = __builtin_amdgcn_mfma_f32_16x16x32_bf16(a2f[i2], hf, p2, 0, 0, 0);       \
    }                                                                               \
    /* wave partial for batch c (all regs/groups equal) */                          \
    if (g == 0) lds_part[CUR][w][c] = p2[0];                                        \
    lds_barrier();                                                                  \
  }

#pragma unroll 1
  for (int t = 1; t + 1 < TT; t += 2) {
    STEP(t, 1, s0a, s0b)
    STEP(t + 1, 0, s1a, s1b)
  }
  STEP(TT - 1, 1, s0a, s0b)  // t = 511 (CUR=1, writes lds_part[1])

  // final: pred_511 from lds_part[1]
  {
    const float* pp = &lds_part[1][0][c];
    const float pc = ((pp[0] + pp[16]) + (pp[32] + pp[48])) +
                     ((pp[64] + pp[80]) + (pp[96] + pp[112]));
    if (w == 0 && g == 0) out[(long)(br + c) * TT + (TT - 1)] = pc;
  }
#undef STEP
}

extern "C" void kernel_launch(void* const* d_in, const int* in_sizes, int n_in,
                              void* d_out, int out_size, void* d_ws, size_t ws_size,
                              hipStream_t stream) {
  const float* x   = (const float*)d_in[0];
  // d_in[1] = labels (unused by the reference forward pass)
  const float* W1  = (const float*)d_in[2];
  const float* b1  = (const float*)d_in[3];
  const float* W2  = (const float*)d_in[4];
  const float* b2  = (const float*)d_in[5];
  float* out = (float*)d_out;

  ffnn_ar_kernel<<<256, 512, 0, stream>>>(x, W1, b1, W2, b2, out);
}

// Round 11
// 389.697 us; speedup vs baseline: 3.6116x; 1.3223x over previous
//
#include <hip/hip_runtime.h>

// Autoregressive FFNN. out[b,0]=0; t=1..511: mi=[x[b,t,:],pred]; h=relu(mi@W1+b1); pred=h@W2+b2.
// B=4096,T=512,F=63. 256 WGs x 512 thr (8 waves), 16 rows/WG, persistent, 1 raw barrier/step.
// R8 structure (operand-swapped MFMA: A=W1^T, B=x -> z[hidden][batch=c]; pred into B k=63 slot;
// b1 as MFMA C-init; layer2 via MFMA with replicated-row W2 frags; 8-read broadcast gather).
// R9: layer-2 in fp16 — h packed with v_cvt_pkrtz_f16_f32 (1 instr / 2 floats) instead of
// manual bf16 bit-twiddle (~160 VALU -> ~40), W2 frags cast to f16 (same layout, dtype-indep),
// layer-2 MFMA chain split into two parallel accumulators.

#define TT 512
#define FF 63
#define HID 1024

typedef __attribute__((ext_vector_type(8))) short short8;
typedef __attribute__((ext_vector_type(4))) float f32x4;
typedef __attribute__((ext_vector_type(4))) int i32x4;
typedef __attribute__((ext_vector_type(8))) _Float16 h16x8;

__device__ __forceinline__ unsigned short f2bf(float f) {
  union { float f; unsigned u; } v; v.f = f;
  unsigned r = v.u + 0x7FFFu + ((v.u >> 16) & 1u);  // RNE
  return (unsigned short)(r >> 16);
}

// LDS-visibility barrier WITHOUT the vmcnt(0) drain of __syncthreads.
__device__ __forceinline__ void lds_barrier() {
  asm volatile("s_waitcnt lgkmcnt(0)" ::: "memory");
  __builtin_amdgcn_s_barrier();
  asm volatile("" ::: "memory");
}

// pack relu(a),relu(b) -> 2xf16 (RTZ, v_cvt_pkrtz_f16_f32) as int
__device__ __forceinline__ int pkh(float a, float b) {
  auto h = __builtin_amdgcn_cvt_pkrtz(fmaxf(a, 0.f), fmaxf(b, 0.f));
  return __builtin_bit_cast(int, h);
}

__global__ __launch_bounds__(512, 2)
void ffnn_ar_kernel(const float* __restrict__ x,
                    const float* __restrict__ W1,
                    const float* __restrict__ b1,
                    const float* __restrict__ W2,
                    const float* __restrict__ b2p,
                    float* __restrict__ out) {
  __shared__ __align__(16) unsigned short lds_A[2][16][72];  // bf16 x-tiles (col63 unused)
  __shared__ __align__(16) float lds_part[2][8][16];         // [buf][wave][batch c]

  const int tid  = threadIdx.x;
  const int lane = tid & 63;
  const int w    = tid >> 6;    // wave 0..7: hidden cols [128w, 128w+128)
  const int c    = lane & 15;   // batch column (C col) / frag row-id
  const int g    = lane >> 4;   // k-group
  const int br   = blockIdx.x * 16;

  // ---- one-time weights ----
  // bfr[i][ks]: A1-frag = W1^T: lane (c,g) slot j = W1[ks*32+g*8+j][(w*8+i)*16+c]
  short8 bfr[8][2];
#pragma unroll
  for (int i = 0; i < 8; ++i) {
    const int n = (w * 8 + i) * 16 + c;
#pragma unroll
    for (int ks = 0; ks < 2; ++ks) {
      short8 f;
#pragma unroll
      for (int j = 0; j < 8; ++j) f[j] = (short)f2bf(W1[(ks * 32 + g * 8 + j) * HID + n]);
      bfr[i][ks] = f;
    }
  }
  // b1v[i]: C-init, lane (c,g) reg q = b1[(w*8+i)*16 + g*4 + q]
  f32x4 b1v[8];
#pragma unroll
  for (int i = 0; i < 8; ++i) {
    const int nb = (w * 8 + i) * 16 + g * 4;
    b1v[i] = (f32x4){b1[nb], b1[nb + 1], b1[nb + 2], b1[nb + 3]};
  }
  // a2f[i2]: f16 A2-frag (rows replicated): slot j = W2[(w*8+2*i2+(j>>2))*16 + g*4 + (j&3)]
  h16x8 a2f[4];
#pragma unroll
  for (int i2 = 0; i2 < 4; ++i2) {
    h16x8 f;
#pragma unroll
    for (int j = 0; j < 8; ++j)
      f[j] = (_Float16)W2[(w * 8 + 2 * i2 + (j >> 2)) * 16 + g * 4 + (j & 3)];
    a2f[i2] = f;
  }
  const float b2 = b2p[0];
  const float b2w = (w == 0) ? b2 : 0.f;  // baked once via wave0's layer-2 C-init

  // ---- x staging: 16 groups of 32 threads, one row each (R5-proven) ----
  const int srow = tid >> 5;   // 0..15
  const int sl   = tid & 31;   // 0..31
  const long rowbase = (long)(br + srow) * (TT * FF);

  // prologue
  lds_A[1][srow][sl] = f2bf(x[rowbase + FF + sl]);
  if (sl < 31) lds_A[1][srow][32 + sl] = f2bf(x[rowbase + FF + 32 + sl]);
  if (tid < 128) reinterpret_cast<float*>(lds_part)[tid] = 0.f;  // buf0 = 0 -> pred_0 = 0
  if (tid < 16) out[(long)(br + tid) * TT] = 0.f;                // out[:,0] = 0

  float s0a = x[rowbase + 2 * FF + sl];
  float s0b = (sl < 31) ? x[rowbase + 2 * FF + 32 + sl] : 0.f;
  float s1a = x[rowbase + 3 * FF + sl];
  float s1b = (sl < 31) ? x[rowbase + 3 * FF + 32 + sl] : 0.f;

  lds_barrier();

#define STEP(T, CUR, SA, SB)                                                        \
  {                                                                                 \
    /* gather pred_{T-1}[batch c]: 8 broadcast b32 reads + tree (b2 already baked)*/\
    const float* pp = &lds_part[(CUR) ^ 1][0][c];                                   \
    const float pc = ((pp[0] + pp[16]) + (pp[32] + pp[48])) +                       \
                     ((pp[64] + pp[80]) + (pp[96] + pp[112]));                      \
    if (w == 0 && g == 0) out[(long)(br + c) * TT + ((T) - 1)] = pc;                \
    /* B-frags for x_T; inject pred into k=63 slot (g==3, elem 7) */                \
    const short8 xb0 = *reinterpret_cast<const short8*>(&lds_A[CUR][c][g * 8]);     \
    short8 xb1 = *reinterpret_cast<const short8*>(&lds_A[CUR][c][32 + g * 8]);      \
    if (g == 3) xb1[7] = (short)f2bf(pc);                                           \
    /* layer1: A=W1^T (bfr), B=x, C-init=b1 -> z[hidden g*4+q + 16i][batch c] */    \
    f32x4 acc[8];                                                                   \
    _Pragma("unroll") for (int i = 0; i < 8; ++i) {                                 \
      f32x4 z4 = __builtin_amdgcn_mfma_f32_16x16x32_bf16(bfr[i][0], xb0, b1v[i], 0, 0, 0); \
      acc[i] = __builtin_amdgcn_mfma_f32_16x16x32_bf16(bfr[i][1], xb1, z4, 0, 0, 0);\
    }                                                                               \
    /* stage x_{T+1}; prefetch x_{T+3} (stays in flight across raw barrier) */      \
    lds_A[(CUR) ^ 1][srow][sl] = f2bf(SA);                                          \
    if (sl < 31) lds_A[(CUR) ^ 1][srow][32 + sl] = f2bf(SB);                        \
    {                                                                               \
      const int tp = ((T) + 3 < TT) ? (T) + 3 : TT - 1;                             \
      SA = x[rowbase + (long)tp * FF + sl];                                         \
      if (sl < 31) SB = x[rowbase + (long)tp * FF + 32 + sl];                       \
    }                                                                               \
    /* h = relu(z) packed to f16 via v_cvt_pkrtz; layer-2 = 4 MFMAs, 2 par chains */\
    f32x4 p2a = {b2w, b2w, b2w, b2w};                                               \
    f32x4 p2b = {0.f, 0.f, 0.f, 0.f};                                               \
    _Pragma("unroll") for (int i2 = 0; i2 < 4; ++i2) {                              \
      const f32x4 u = acc[2 * i2], v = acc[2 * i2 + 1];                             \
      const h16x8 hf = __builtin_bit_cast(h16x8, (i32x4){                           \
          pkh(u[0], u[1]), pkh(u[2], u[3]), pkh(v[0], v[1]), pkh(v[2], v[3])});     \
      if (i2 & 1)                                                                   \
        p2b = __builtin_amdgcn_mfma_f32_16x16x32_f16(a2f[i2], hf, p2b, 0, 0, 0);    \
      else                                                                          \
        p2a = __builtin_amdgcn_mfma_f32_16x16x32_f16(a2f[i2], hf, p2a, 0, 0, 0);    \
    }                                                                               \
    /* wave partial for batch c (all regs/groups equal) */                          \
    if (g == 0) lds_part[CUR][w][c] = p2a[0] + p2b[0];                              \
    lds_barrier();                                                                  \
  }

#pragma unroll 1
  for (int t = 1; t + 1 < TT; t += 2) {
    STEP(t, 1, s0a, s0b)
    STEP(t + 1, 0, s1a, s1b)
  }
  STEP(TT - 1, 1, s0a, s0b)  // t = 511 (CUR=1, writes lds_part[1])

  // final: pred_511 from lds_part[1]
  {
    const float* pp = &lds_part[1][0][c];
    const float pc = ((pp[0] + pp[16]) + (pp[32] + pp[48])) +
                     ((pp[64] + pp[80]) + (pp[96] + pp[112]));
    if (w == 0 && g == 0) out[(long)(br + c) * TT + (TT - 1)] = pc;
  }
#undef STEP
}

extern "C" void kernel_launch(void* const* d_in, const int* in_sizes, int n_in,
                              void* d_out, int out_size, void* d_ws, size_t ws_size,
                              hipStream_t stream) {
  const float* x   = (const float*)d_in[0];
  // d_in[1] = labels (unused by the reference forward pass)
  const float* W1  = (const float*)d_in[2];
  const float* b1  = (const float*)d_in[3];
  const float* W2  = (const float*)d_in[4];
  const float* b2  = (const float*)d_in[5];
  float* out = (float*)d_out;

  ffnn_ar_kernel<<<256, 512, 0, stream>>>(x, W1, b1, W2, b2, out);
}

// Round 12
// 349.691 us; speedup vs baseline: 4.0248x; 1.1144x over previous
//
#include <hip/hip_runtime.h>

// Autoregressive FFNN. out[b,0]=0; t=1..511: mi=[x[b,t,:],pred]; h=relu(mi@W1+b1); pred=h@W2+b2.
// B=4096,T=512,F=63. 256 WGs x 512 thr (8 waves), 16 rows/WG, persistent, 1 raw barrier/step.
// R11: all-f16 datapath. Layer1: A=W1^T (f16 frags), B=x (f16, staged via v_cvt_f16_f32),
// C-init=b1 -> z[hidden][batch=c]. Pred feedback moved OFF the MFMA operand path back to
// VALU (acc += pc*W1[63][n]) so layer-1 MFMAs issue immediately after the barrier and the
// pred gather (2x ds_read_b128 from transposed [16][12] partials + 7-add tree) overlaps
// with MFMA latency. h packed via v_cvt_pkrtz; layer2 = 4 f16 MFMAs, 2 parallel chains.

#define TT 512
#define FF 63
#define HID 1024

typedef __attribute__((ext_vector_type(4))) float f32x4;
typedef __attribute__((ext_vector_type(4))) int i32x4;
typedef __attribute__((ext_vector_type(8))) _Float16 h16x8;

// LDS-visibility barrier WITHOUT the vmcnt(0) drain of __syncthreads.
__device__ __forceinline__ void lds_barrier() {
  asm volatile("s_waitcnt lgkmcnt(0)" ::: "memory");
  __builtin_amdgcn_s_barrier();
  asm volatile("" ::: "memory");
}

// pack relu(a),relu(b) -> 2xf16 (RTZ, v_cvt_pkrtz_f16_f32) as int
__device__ __forceinline__ int pkh(float a, float b) {
  auto h = __builtin_amdgcn_cvt_pkrtz(fmaxf(a, 0.f), fmaxf(b, 0.f));
  return __builtin_bit_cast(int, h);
}

__global__ __launch_bounds__(512, 2)
void ffnn_ar_kernel(const float* __restrict__ x,
                    const float* __restrict__ W1,
                    const float* __restrict__ b1,
                    const float* __restrict__ W2,
                    const float* __restrict__ b2p,
                    float* __restrict__ out) {
  __shared__ __align__(16) _Float16 lds_A[2][16][72];  // f16 x-tiles (col63 = 0), 144B rows
  __shared__ __align__(16) float lds_part[2][16][12];  // [buf][batch c][wave w], 48B rows

  const int tid  = threadIdx.x;
  const int lane = tid & 63;
  const int w    = tid >> 6;    // wave 0..7: hidden cols [128w, 128w+128)
  const int c    = lane & 15;   // batch column (C col) / frag row-id
  const int g    = lane >> 4;   // k-group
  const int br   = blockIdx.x * 16;

  // ---- one-time weights ----
  // bfr[i][ks]: A1-frag = W1^T (f16): lane (c,g) slot j = W1[ks*32+g*8+j][(w*8+i)*16+c]
  h16x8 bfr[8][2];
#pragma unroll
  for (int i = 0; i < 8; ++i) {
    const int n = (w * 8 + i) * 16 + c;
#pragma unroll
    for (int ks = 0; ks < 2; ++ks) {
      h16x8 f;
#pragma unroll
      for (int j = 0; j < 8; ++j) f[j] = (_Float16)W1[(ks * 32 + g * 8 + j) * HID + n];
      bfr[i][ks] = f;
    }
  }
  // b1v[i]: C-init, lane (c,g) reg q = b1[(w*8+i)*16 + g*4 + q]
  // w63v[i]: feedback weights W1[63][same n] (f32, VALU fma)
  f32x4 b1v[8], w63v[8];
#pragma unroll
  for (int i = 0; i < 8; ++i) {
    const int nb = (w * 8 + i) * 16 + g * 4;
    b1v[i]  = (f32x4){b1[nb], b1[nb + 1], b1[nb + 2], b1[nb + 3]};
    w63v[i] = (f32x4){W1[63 * HID + nb], W1[63 * HID + nb + 1],
                      W1[63 * HID + nb + 2], W1[63 * HID + nb + 3]};
  }
  // a2f[i2]: f16 A2-frag (rows replicated): slot j = W2[(w*8+2*i2+(j>>2))*16 + g*4 + (j&3)]
  h16x8 a2f[4];
#pragma unroll
  for (int i2 = 0; i2 < 4; ++i2) {
    h16x8 f;
#pragma unroll
    for (int j = 0; j < 8; ++j)
      f[j] = (_Float16)W2[(w * 8 + 2 * i2 + (j >> 2)) * 16 + g * 4 + (j & 3)];
    a2f[i2] = f;
  }
  const float b2 = b2p[0];
  const float b2w = (w == 0) ? b2 : 0.f;  // baked once via wave0's layer-2 C-init

  // ---- x staging: 16 groups of 32 threads, one row each ----
  const int srow = tid >> 5;   // 0..15
  const int sl   = tid & 31;   // 0..31
  const long rowbase = (long)(br + srow) * (TT * FF);

  // prologue
  lds_A[1][srow][sl] = (_Float16)x[rowbase + FF + sl];
  if (sl < 31) lds_A[1][srow][32 + sl] = (_Float16)x[rowbase + FF + 32 + sl];
  if (tid < 16) { lds_A[0][tid][63] = (_Float16)0.f; lds_A[1][tid][63] = (_Float16)0.f; }
  if (tid < 384) reinterpret_cast<float*>(lds_part)[tid] = 0.f;  // both bufs -> pred_0 = 0
  if (tid < 16) out[(long)(br + tid) * TT] = 0.f;                // out[:,0] = 0

  float s0a = x[rowbase + 2 * FF + sl];
  float s0b = (sl < 31) ? x[rowbase + 2 * FF + 32 + sl] : 0.f;
  float s1a = x[rowbase + 3 * FF + sl];
  float s1b = (sl < 31) ? x[rowbase + 3 * FF + 32 + sl] : 0.f;

  lds_barrier();

#define STEP(T, CUR, SA, SB)                                                        \
  {                                                                                 \
    /* x frags (f16) — no pred dependency: MFMAs can issue immediately */           \
    const h16x8 xb0 = *reinterpret_cast<const h16x8*>(&lds_A[CUR][c][g * 8]);       \
    const h16x8 xb1 = *reinterpret_cast<const h16x8*>(&lds_A[CUR][c][32 + g * 8]);  \
    /* gather pred_{T-1}[batch c]: 2x ds_read_b128 + 7-add tree (overlaps MFMA) */  \
    const f32x4 v0 = *reinterpret_cast<const f32x4*>(&lds_part[(CUR) ^ 1][c][0]);   \
    const f32x4 v1 = *reinterpret_cast<const f32x4*>(&lds_part[(CUR) ^ 1][c][4]);   \
    const float pc = ((v0[0] + v0[1]) + (v0[2] + v0[3])) +                          \
                     ((v1[0] + v1[1]) + (v1[2] + v1[3]));                           \
    /* layer1: A=W1^T (f16), B=x, C-init=b1 -> z[hidden g*4+q + 16i][batch c] */    \
    f32x4 acc[8];                                                                   \
    _Pragma("unroll") for (int i = 0; i < 8; ++i) {                                 \
      f32x4 z4 = __builtin_amdgcn_mfma_f32_16x16x32_f16(bfr[i][0], xb0, b1v[i], 0, 0, 0); \
      acc[i] = __builtin_amdgcn_mfma_f32_16x16x32_f16(bfr[i][1], xb1, z4, 0, 0, 0); \
    }                                                                               \
    if (w == 0 && g == 0) out[(long)(br + c) * TT + ((T) - 1)] = pc;                \
    /* stage x_{T+1}; prefetch x_{T+3} (stays in flight across raw barrier) */      \
    lds_A[(CUR) ^ 1][srow][sl] = (_Float16)SA;                                      \
    if (sl < 31) lds_A[(CUR) ^ 1][srow][32 + sl] = (_Float16)SB;                    \
    {                                                                               \
      const int tp = ((T) + 3 < TT) ? (T) + 3 : TT - 1;                             \
      SA = x[rowbase + (long)tp * FF + sl];                                         \
      if (sl < 31) SB = x[rowbase + (long)tp * FF + 32 + sl];                       \
    }                                                                               \
    /* epilogue: z += pc*W1[63]; h=relu(z) packed f16; layer2 = 4 MFMAs, 2 chains */\
    f32x4 p2a = {b2w, b2w, b2w, b2w};                                               \
    f32x4 p2b = {0.f, 0.f, 0.f, 0.f};                                               \
    _Pragma("unroll") for (int i2 = 0; i2 < 4; ++i2) {                              \
      const f32x4 u = acc[2 * i2], v = acc[2 * i2 + 1];                             \
      const f32x4 wu = w63v[2 * i2], wv = w63v[2 * i2 + 1];                         \
      const h16x8 hf = __builtin_bit_cast(h16x8, (i32x4){                           \
          pkh(fmaf(pc, wu[0], u[0]), fmaf(pc, wu[1], u[1])),                        \
          pkh(fmaf(pc, wu[2], u[2]), fmaf(pc, wu[3], u[3])),                        \
          pkh(fmaf(pc, wv[0], v[0]), fmaf(pc, wv[1], v[1])),                        \
          pkh(fmaf(pc, wv[2], v[2]), fmaf(pc, wv[3], v[3]))});                      \
      if (i2 & 1)                                                                   \
        p2b = __builtin_amdgcn_mfma_f32_16x16x32_f16(a2f[i2], hf, p2b, 0, 0, 0);    \
      else                                                                          \
        p2a = __builtin_amdgcn_mfma_f32_16x16x32_f16(a2f[i2], hf, p2a, 0, 0, 0);    \
    }                                                                               \
    /* wave partial for batch c -> transposed layout [c][w] */                      \
    if (g == 0) lds_part[CUR][c][w] = p2a[0] + p2b[0];                              \
    lds_barrier();                                                                  \
  }

#pragma unroll 1
  for (int t = 1; t + 1 < TT; t += 2) {
    STEP(t, 1, s0a, s0b)
    STEP(t + 1, 0, s1a, s1b)
  }
  STEP(TT - 1, 1, s0a, s0b)  // t = 511 (CUR=1, writes lds_part[1])

  // final: pred_511 from lds_part[1]
  {
    const f32x4 v0 = *reinterpret_cast<const f32x4*>(&lds_part[1][c][0]);
    const f32x4 v1 = *reinterpret_cast<const f32x4*>(&lds_part[1][c][4]);
    const float pc = ((v0[0] + v0[1]) + (v0[2] + v0[3])) +
                     ((v1[0] + v1[1]) + (v1[2] + v1[3]));
    if (w == 0 && g == 0) out[(long)(br + c) * TT + (TT - 1)] = pc;
  }
#undef STEP
}

extern "C" void kernel_launch(void* const* d_in, const int* in_sizes, int n_in,
                              void* d_out, int out_size, void* d_ws, size_t ws_size,
                              hipStream_t stream) {
  const float* x   = (const float*)d_in[0];
  // d_in[1] = labels (unused by the reference forward pass)
  const float* W1  = (const float*)d_in[2];
  const float* b1  = (const float*)d_in[3];
  const float* W2  = (const float*)d_in[4];
  const float* b2  = (const float*)d_in[5];
  float* out = (float*)d_out;

  ffnn_ar_kernel<<<256, 512, 0, stream>>>(x, W1, b1, W2, b2, out);
}